// Round 2
// baseline (340.277 us; speedup 1.0000x reference)
//
#include <hip/hip_runtime.h>
#include <hip/hip_bf16.h>
#include <stdint.h>

#define B_  2
#define S_  2048
#define D_  1024
#define H_  16
#define HD_ 64
#define M_  (B_*S_)   // 4096 tokens

typedef __attribute__((ext_vector_type(8))) short short8;
typedef __attribute__((ext_vector_type(4))) float f32x4;

// fp32 -> bf16 round-to-nearest-even
__device__ __forceinline__ unsigned short f2bf(float f) {
  union { float f; unsigned int u; } x; x.f = f;
  unsigned int r = (x.u + 0x7FFFu + ((x.u >> 16) & 1u)) >> 16;
  return (unsigned short)r;
}

typedef const __attribute__((address_space(1))) unsigned int* gas1_t;
typedef __attribute__((address_space(3))) unsigned int* las3_t;

// async global->LDS, 16B per lane; LDS dest is wave-uniform base + lane*16 (HW)
__device__ __forceinline__ void gload_lds16(const void* g, void* l) {
  __builtin_amdgcn_global_load_lds((gas1_t)g, (las3_t)l, 16, 0, 0);
}

// ---------------- elementwise fp32 -> bf16 ----------------
__global__ void k_cvt_bf16(const float* __restrict__ x, ushort* __restrict__ o, int n4) {
  int i = blockIdx.x * blockDim.x + threadIdx.x;
  int stride = gridDim.x * blockDim.x;
  for (int j = i; j < n4; j += stride) {
    float4 v = ((const float4*)x)[j];
    ushort4 u = make_ushort4(f2bf(v.x), f2bf(v.y), f2bf(v.z), f2bf(v.w));
    ((ushort4*)o)[j] = u;
  }
}

// ---------------- W [k][n] fp32 -> Wt [n][k] bf16 (tiled transpose) ----------------
__global__ void k_transpose_w(const float* __restrict__ w0, const float* __restrict__ w1,
                              const float* __restrict__ w2, const float* __restrict__ w3,
                              ushort* __restrict__ o0, ushort* __restrict__ o1,
                              ushort* __restrict__ o2, ushort* __restrict__ o3) {
  const float* w = (blockIdx.z == 0) ? w0 : (blockIdx.z == 1) ? w1 : (blockIdx.z == 2) ? w2 : w3;
  ushort*      o = (blockIdx.z == 0) ? o0 : (blockIdx.z == 1) ? o1 : (blockIdx.z == 2) ? o2 : o3;
  __shared__ float t[32][33];
  int tx = threadIdx.x & 31, ty = threadIdx.x >> 5;   // 256 threads: 32 x 8
  int kt = blockIdx.y * 32, nt = blockIdx.x * 32;
  #pragma unroll
  for (int i = 0; i < 4; ++i)
    t[ty + 8 * i][tx] = w[(size_t)(kt + ty + 8 * i) * D_ + nt + tx];
  __syncthreads();
  #pragma unroll
  for (int i = 0; i < 4; ++i)
    o[(size_t)(nt + ty + 8 * i) * D_ + kt + tx] = f2bf(t[tx][ty + 8 * i]);
}

// ---------------- bf16 GEMM: out[tok][n] = A[tok][:] . Bt[n][:] + bias[n] ----------------
// 128x128 tile, BK=64, 4 waves, double-buffered LDS, global_load_lds w/ source-side XOR swizzle.
// mode 0: Q (scaled, bf16 [b,h,s,hd])  1: K (bf16 [b,h,s,hd])
// mode 2: V^T (bf16 [b,h,hd,s])        3: O (fp32 [tok][n])
__global__ __launch_bounds__(256) void k_gemm_bt(const ushort* __restrict__ A,
                                                 const ushort* __restrict__ Bt,
                                                 const float* __restrict__ bias,
                                                 void* __restrict__ outp, int mode) {
  __shared__ char smem[2][32768];   // per buffer: A tile 16K | B tile 16K
  const int tid = threadIdx.x;
  const int w = tid >> 6, lane = tid & 63;
  const int g = lane >> 4, c = lane & 15;
  const int m0 = blockIdx.y * 128, n0 = blockIdx.x * 128;
  const int wm = (w >> 1) * 64, wn = (w & 1) * 64;

  f32x4 acc[4][4];
  #pragma unroll
  for (int i = 0; i < 4; ++i)
    #pragma unroll
    for (int j = 0; j < 4; ++j) acc[i][j] = 0.f;

  const char* Abase = (const char*)A + (size_t)m0 * (D_ * 2);
  const char* Bbase = (const char*)Bt + (size_t)n0 * (D_ * 2);

  auto stage = [&](int buf, int kb) {
    char* ls = &smem[buf][0];
    #pragma unroll
    for (int i = 0; i < 4; ++i) {
      int obase = w * 4096 + i * 1024;
      int ot = obase + lane * 16;
      int u = ot ^ (((ot >> 7) & 7) << 4);        // inverse swizzle on SOURCE (rule #21)
      gload_lds16(Abase + (size_t)(u >> 7) * (D_ * 2) + kb * 128 + (u & 127), ls + obase);
    }
    #pragma unroll
    for (int i = 0; i < 4; ++i) {
      int obase = w * 4096 + i * 1024;
      int ot = obase + lane * 16;
      int u = ot ^ (((ot >> 7) & 7) << 4);
      gload_lds16(Bbase + (size_t)(u >> 7) * (D_ * 2) + kb * 128 + (u & 127), ls + 16384 + obase);
    }
  };

  stage(0, 0);
  int cur = 0;
  for (int kb = 0; kb < D_ / 64; ++kb) {
    __syncthreads();                       // drains vmcnt: buf[cur] staged; prev reads done
    if (kb < D_ / 64 - 1) stage(cur ^ 1, kb + 1);   // prefetch hides under compute
    const char* lsA = &smem[cur][0];
    const char* lsB = lsA + 16384;
    short8 a[4][2], b[4][2];
    #pragma unroll
    for (int f = 0; f < 4; ++f) {
      int rowA = wm + f * 16 + c;
      int rowB = wn + f * 16 + c;
      #pragma unroll
      for (int ks = 0; ks < 2; ++ks) {
        int offA = (rowA * 128 + ks * 64 + g * 16) ^ ((rowA & 7) << 4);
        int offB = (rowB * 128 + ks * 64 + g * 16) ^ ((rowB & 7) << 4);
        a[f][ks] = *(const short8*)(lsA + offA);
        b[f][ks] = *(const short8*)(lsB + offB);
      }
    }
    #pragma unroll
    for (int mf = 0; mf < 4; ++mf)
      #pragma unroll
      for (int nf = 0; nf < 4; ++nf) {
        acc[mf][nf] = __builtin_amdgcn_mfma_f32_16x16x32_bf16(a[mf][0], b[nf][0], acc[mf][nf], 0, 0, 0);
        acc[mf][nf] = __builtin_amdgcn_mfma_f32_16x16x32_bf16(a[mf][1], b[nf][1], acc[mf][nf], 0, 0, 0);
      }
    cur ^= 1;
  }

  // epilogue: C/D layout col=lane&15, row=4*(lane>>4)+reg (verified m89/m91)
  #pragma unroll
  for (int nf = 0; nf < 4; ++nf) {
    int col = n0 + wn + nf * 16 + c;
    float bv = bias[col];
    #pragma unroll
    for (int mf = 0; mf < 4; ++mf) {
      #pragma unroll
      for (int r = 0; r < 4; ++r) {
        int tok = m0 + wm + mf * 16 + 4 * g + r;
        float v = acc[mf][nf][r] + bv;
        if (mode == 3) {
          ((float*)outp)[(size_t)tok * D_ + col] = v;
        } else {
          if (mode == 0) v *= 0.18033688011112042f;   // (1/8)*log2(e): exp2-domain softmax
          int bi = tok >> 11, si = tok & 2047;
          int h = col >> 6, hd = col & 63;
          size_t off = (mode == 2)
            ? ((size_t)(bi * H_ + h) * HD_ + hd) * S_ + si     // V^T
            : ((size_t)(bi * H_ + h) * S_ + si) * HD_ + hd;    // Q / K
          ((ushort*)outp)[off] = f2bf(v);
        }
      }
    }
  }
}

// ---------------- flash attention: 4 waves x 32 Q-rows, 32-key chunks ----------------
__global__ __launch_bounds__(256) void k_attn(const ushort* __restrict__ Q,
                                              const ushort* __restrict__ K,
                                              const ushort* __restrict__ Vt,
                                              ushort* __restrict__ O) {
  __shared__ char plds[8192];            // per-wave 2KB P scratch (no cross-wave sharing)
  const int tid = threadIdx.x;
  const int w = tid >> 6, lane = tid & 63;
  const int g = lane >> 4, c = lane & 15;
  const int bh = blockIdx.y, qt = blockIdx.x;
  const int q0 = qt * 128 + w * 32;
  const ushort* Qb = Q + (size_t)bh * S_ * HD_;
  const ushort* Kb = K + (size_t)bh * S_ * HD_;
  const ushort* Vb = Vt + (size_t)bh * HD_ * S_;
  char* pw = plds + w * 2048;

  short8 aq[2][2];
  #pragma unroll
  for (int mt = 0; mt < 2; ++mt)
    #pragma unroll
    for (int ks = 0; ks < 2; ++ks)
      aq[mt][ks] = *(const short8*)(Qb + (size_t)(q0 + mt * 16 + c) * HD_ + ks * 32 + g * 8);

  f32x4 aco[2][4];
  float mrun[2][4], lrun[2][4];
  #pragma unroll
  for (int mt = 0; mt < 2; ++mt) {
    #pragma unroll
    for (int dt = 0; dt < 4; ++dt) aco[mt][dt] = 0.f;
    #pragma unroll
    for (int r = 0; r < 4; ++r) { mrun[mt][r] = -1e30f; lrun[mt][r] = 0.f; }
  }

  for (int kc = 0; kc < S_ / 32; ++kc) {
    const int k0 = kc * 32;
    short8 bk[2][2];
    #pragma unroll
    for (int nt = 0; nt < 2; ++nt)
      #pragma unroll
      for (int ks = 0; ks < 2; ++ks)
        bk[nt][ks] = *(const short8*)(Kb + (size_t)(k0 + nt * 16 + c) * HD_ + ks * 32 + g * 8);

    f32x4 s[2][2];
    #pragma unroll
    for (int mt = 0; mt < 2; ++mt)
      #pragma unroll
      for (int nt = 0; nt < 2; ++nt) {
        s[mt][nt] = 0.f;
        s[mt][nt] = __builtin_amdgcn_mfma_f32_16x16x32_bf16(aq[mt][0], bk[nt][0], s[mt][nt], 0, 0, 0);
        s[mt][nt] = __builtin_amdgcn_mfma_f32_16x16x32_bf16(aq[mt][1], bk[nt][1], s[mt][nt], 0, 0, 0);
      }

    float mnew[2][4], sc[2][4];
    #pragma unroll
    for (int mt = 0; mt < 2; ++mt)
      #pragma unroll
      for (int r = 0; r < 4; ++r) {
        float t = fmaxf(s[mt][0][r], s[mt][1][r]);
        t = fmaxf(t, __shfl_xor(t, 1, 64));
        t = fmaxf(t, __shfl_xor(t, 2, 64));
        t = fmaxf(t, __shfl_xor(t, 4, 64));
        t = fmaxf(t, __shfl_xor(t, 8, 64));
        mnew[mt][r] = fmaxf(mrun[mt][r], t);
        sc[mt][r] = exp2f(mrun[mt][r] - mnew[mt][r]);
      }

    #pragma unroll
    for (int mt = 0; mt < 2; ++mt) {
      float rs[4] = {0.f, 0.f, 0.f, 0.f};
      #pragma unroll
      for (int nt = 0; nt < 2; ++nt)
        #pragma unroll
        for (int r = 0; r < 4; ++r) {
          float p = exp2f(s[mt][nt][r] - mnew[mt][r]);
          rs[r] += p;
          int off = (16 * mt + 4 * g + r) * 64 + (16 * nt + c) * 2;
          off ^= ((off >> 6) & 3) << 4;
          *(ushort*)(pw + off) = f2bf(p);
        }
      #pragma unroll
      for (int r = 0; r < 4; ++r) {
        float t = rs[r];
        t += __shfl_xor(t, 1, 64);
        t += __shfl_xor(t, 2, 64);
        t += __shfl_xor(t, 4, 64);
        t += __shfl_xor(t, 8, 64);
        lrun[mt][r] = lrun[mt][r] * sc[mt][r] + t;
        mrun[mt][r] = mnew[mt][r];
      }
    }

    #pragma unroll
    for (int mt = 0; mt < 2; ++mt)
      #pragma unroll
      for (int dt = 0; dt < 4; ++dt)
        #pragma unroll
        for (int r = 0; r < 4; ++r) aco[mt][dt][r] *= sc[mt][r];

    short8 bv[4], ap[2];
    #pragma unroll
    for (int dt = 0; dt < 4; ++dt)
      bv[dt] = *(const short8*)(Vb + (size_t)(dt * 16 + c) * S_ + k0 + g * 8);
    #pragma unroll
    for (int mt = 0; mt < 2; ++mt) {
      int off = (mt * 16 + c) * 64 + g * 16;
      off ^= ((off >> 6) & 3) << 4;
      ap[mt] = *(const short8*)(pw + off);   // same-wave ds_write->ds_read: compiler waits
    }
    #pragma unroll
    for (int mt = 0; mt < 2; ++mt)
      #pragma unroll
      for (int dt = 0; dt < 4; ++dt)
        aco[mt][dt] = __builtin_amdgcn_mfma_f32_16x16x32_bf16(ap[mt], bv[dt], aco[mt][dt], 0, 0, 0);
  }

  const int bi = bh >> 4, h = bh & 15;
  float inv[2][4];
  #pragma unroll
  for (int mt = 0; mt < 2; ++mt)
    #pragma unroll
    for (int r = 0; r < 4; ++r) inv[mt][r] = 1.f / lrun[mt][r];
  #pragma unroll
  for (int mt = 0; mt < 2; ++mt)
    #pragma unroll
    for (int dt = 0; dt < 4; ++dt)
      #pragma unroll
      for (int r = 0; r < 4; ++r) {
        float v = aco[mt][dt][r] * inv[mt][r];
        int tok = bi * S_ + q0 + mt * 16 + 4 * g + r;
        int dim = h * HD_ + dt * 16 + c;
        O[(size_t)tok * D_ + dim] = f2bf(v);
      }
}

extern "C" void kernel_launch(void* const* d_in, const int* in_sizes, int n_in,
                              void* d_out, int out_size, void* d_ws, size_t ws_size,
                              hipStream_t stream) {
  const float* x  = (const float*)d_in[0];
  const float* Wq = (const float*)d_in[1];
  const float* bq = (const float*)d_in[2];
  const float* Wk = (const float*)d_in[3];
  const float* bk = (const float*)d_in[4];
  const float* Wv = (const float*)d_in[5];
  const float* bv = (const float*)d_in[6];
  const float* Wo = (const float*)d_in[7];
  const float* bo = (const float*)d_in[8];
  char* ws = (char*)d_ws;
  const size_t MB = 1024 * 1024;
  ushort* Xbf = (ushort*)(ws + 0);        // 8 MiB
  ushort* Wtq = (ushort*)(ws + 8  * MB);  // 2 MiB each
  ushort* Wtk = (ushort*)(ws + 10 * MB);
  ushort* Wtv = (ushort*)(ws + 12 * MB);
  ushort* Wto = (ushort*)(ws + 14 * MB);
  ushort* Qb  = (ushort*)(ws + 16 * MB);  // 8 MiB each
  ushort* Kb  = (ushort*)(ws + 24 * MB);
  ushort* Vtb = (ushort*)(ws + 32 * MB);
  ushort* Att = (ushort*)(ws + 0);        // reuse Xbf region (dead after V GEMM)

  k_cvt_bf16<<<1024, 256, 0, stream>>>(x, Xbf, M_ * D_ / 4);
  k_transpose_w<<<dim3(32, 32, 4), 256, 0, stream>>>(Wq, Wk, Wv, Wo, Wtq, Wtk, Wtv, Wto);
  k_gemm_bt<<<dim3(8, 32), 256, 0, stream>>>(Xbf, Wtq, bq, Qb, 0);
  k_gemm_bt<<<dim3(8, 32), 256, 0, stream>>>(Xbf, Wtk, bk, Kb, 1);
  k_gemm_bt<<<dim3(8, 32), 256, 0, stream>>>(Xbf, Wtv, bv, Vtb, 2);
  k_attn<<<dim3(16, 32), 256, 0, stream>>>(Qb, Kb, Vtb, Att);
  k_gemm_bt<<<dim3(8, 32), 256, 0, stream>>>(Att, Wto, bo, d_out, 3);
}

// Round 5
// 335.885 us; speedup vs baseline: 1.0131x; 1.0131x over previous
//
#include <hip/hip_runtime.h>
#include <hip/hip_bf16.h>
#include <stdint.h>

#define B_  2
#define S_  2048
#define D_  1024
#define H_  16
#define HD_ 64
#define M_  (B_*S_)   // 4096 tokens

typedef __attribute__((ext_vector_type(8)))  short short8;
typedef __attribute__((ext_vector_type(4)))  float f32x4;
typedef __attribute__((ext_vector_type(16))) float f32x16;

// fp32 -> bf16 round-to-nearest-even
__device__ __forceinline__ unsigned short f2bf(float f) {
  union { float f; unsigned int u; } x; x.f = f;
  unsigned int r = (x.u + 0x7FFFu + ((x.u >> 16) & 1u)) >> 16;
  return (unsigned short)r;
}

// two f32 -> one u32 of packed bf16 (pure C; no inline asm — round-4 NaN suspect removed)
__device__ __forceinline__ unsigned int pkpair(float a, float b) {
  return (unsigned int)f2bf(a) | ((unsigned int)f2bf(b) << 16);
}

__device__ __forceinline__ short8 pk8(float a0, float a1, float a2, float a3,
                                      float a4, float a5, float a6, float a7) {
  union { unsigned int u[4]; short8 v; } r;
  r.u[0] = pkpair(a0, a1); r.u[1] = pkpair(a2, a3);
  r.u[2] = pkpair(a4, a5); r.u[3] = pkpair(a6, a7);
  return r.v;
}

// build a short8 fragment from two 8-byte chunks
__device__ __forceinline__ short8 ld2x4(const ushort* p0, const ushort* p1) {
  union { struct { unsigned long long a, b; } q; short8 v; } u;
  u.q.a = *(const unsigned long long*)p0;
  u.q.b = *(const unsigned long long*)p1;
  return u.v;
}

typedef const __attribute__((address_space(1))) unsigned int* gas1_t;
typedef __attribute__((address_space(3))) unsigned int* las3_t;

__device__ __forceinline__ void gload_lds16(const void* g, void* l) {
  __builtin_amdgcn_global_load_lds((gas1_t)g, (las3_t)l, 16, 0, 0);
}

// ---------------- elementwise fp32 -> bf16 ----------------
__global__ void k_cvt_bf16(const float* __restrict__ x, ushort* __restrict__ o, int n4) {
  int i = blockIdx.x * blockDim.x + threadIdx.x;
  int stride = gridDim.x * blockDim.x;
  for (int j = i; j < n4; j += stride) {
    float4 v = ((const float4*)x)[j];
    ushort4 u = make_ushort4(f2bf(v.x), f2bf(v.y), f2bf(v.z), f2bf(v.w));
    ((ushort4*)o)[j] = u;
  }
}

// ---------------- W [k][n] fp32 -> Wt [n][k] bf16 (tiled transpose) ----------------
__global__ void k_transpose_w(const float* __restrict__ w0, const float* __restrict__ w1,
                              const float* __restrict__ w2, const float* __restrict__ w3,
                              ushort* __restrict__ o0, ushort* __restrict__ o1,
                              ushort* __restrict__ o2, ushort* __restrict__ o3) {
  const float* w = (blockIdx.z == 0) ? w0 : (blockIdx.z == 1) ? w1 : (blockIdx.z == 2) ? w2 : w3;
  ushort*      o = (blockIdx.z == 0) ? o0 : (blockIdx.z == 1) ? o1 : (blockIdx.z == 2) ? o2 : o3;
  __shared__ float t[32][33];
  int tx = threadIdx.x & 31, ty = threadIdx.x >> 5;   // 256 threads: 32 x 8
  int kt = blockIdx.y * 32, nt = blockIdx.x * 32;
  #pragma unroll
  for (int i = 0; i < 4; ++i)
    t[ty + 8 * i][tx] = w[(size_t)(kt + ty + 8 * i) * D_ + nt + tx];
  __syncthreads();
  #pragma unroll
  for (int i = 0; i < 4; ++i)
    o[(size_t)(nt + ty + 8 * i) * D_ + kt + tx] = f2bf(t[tx][ty + 8 * i]);
}

// ---------------- bf16 GEMM: out[tok][n] = A[tok][:] . Bt[n][:] + bias ----------------
// mode 0: fused QKV (Bt = [3072][1024]; section by n0>>10: Q scaled, K, V^T)
// mode 1: output projection (fp32 out + bo)
__global__ __launch_bounds__(256) void k_gemm_bt(const ushort* __restrict__ A,
                                                 const ushort* __restrict__ Bt,
                                                 const float* __restrict__ b0,
                                                 const float* __restrict__ b1,
                                                 const float* __restrict__ b2,
                                                 void* __restrict__ o0,
                                                 void* __restrict__ o1,
                                                 void* __restrict__ o2, int mode) {
  __shared__ char smem[2][32768];   // per buffer: A tile 16K | B tile 16K
  const int tid = threadIdx.x;
  const int w = tid >> 6, lane = tid & 63;
  const int g = lane >> 4, c = lane & 15;
  const int m0 = blockIdx.y * 128, n0 = blockIdx.x * 128;
  const int wm = (w >> 1) * 64, wn = (w & 1) * 64;

  f32x4 acc[4][4];
  #pragma unroll
  for (int i = 0; i < 4; ++i)
    #pragma unroll
    for (int j = 0; j < 4; ++j) acc[i][j] = 0.f;

  const char* Abase = (const char*)A + (size_t)m0 * (D_ * 2);
  const char* Bbase = (const char*)Bt + (size_t)n0 * (D_ * 2);

  auto stage = [&](int buf, int kb) {
    char* ls = &smem[buf][0];
    #pragma unroll
    for (int i = 0; i < 4; ++i) {
      int obase = w * 4096 + i * 1024;
      int ot = obase + lane * 16;
      int u = ot ^ (((ot >> 7) & 7) << 4);        // inverse swizzle on SOURCE (rule #21)
      gload_lds16(Abase + (size_t)(u >> 7) * (D_ * 2) + kb * 128 + (u & 127), ls + obase);
    }
    #pragma unroll
    for (int i = 0; i < 4; ++i) {
      int obase = w * 4096 + i * 1024;
      int ot = obase + lane * 16;
      int u = ot ^ (((ot >> 7) & 7) << 4);
      gload_lds16(Bbase + (size_t)(u >> 7) * (D_ * 2) + kb * 128 + (u & 127), ls + 16384 + obase);
    }
  };

  stage(0, 0);
  int cur = 0;
  for (int kb = 0; kb < D_ / 64; ++kb) {
    __syncthreads();
    if (kb < D_ / 64 - 1) stage(cur ^ 1, kb + 1);
    const char* lsA = &smem[cur][0];
    const char* lsB = lsA + 16384;
    short8 a[4][2], b[4][2];
    #pragma unroll
    for (int f = 0; f < 4; ++f) {
      int rowA = wm + f * 16 + c;
      int rowB = wn + f * 16 + c;
      #pragma unroll
      for (int ks = 0; ks < 2; ++ks) {
        int offA = (rowA * 128 + ks * 64 + g * 16) ^ ((rowA & 7) << 4);
        int offB = (rowB * 128 + ks * 64 + g * 16) ^ ((rowB & 7) << 4);
        a[f][ks] = *(const short8*)(lsA + offA);
        b[f][ks] = *(const short8*)(lsB + offB);
      }
    }
    #pragma unroll
    for (int mf = 0; mf < 4; ++mf)
      #pragma unroll
      for (int nf = 0; nf < 4; ++nf) {
        acc[mf][nf] = __builtin_amdgcn_mfma_f32_16x16x32_bf16(a[mf][0], b[nf][0], acc[mf][nf], 0, 0, 0);
        acc[mf][nf] = __builtin_amdgcn_mfma_f32_16x16x32_bf16(a[mf][1], b[nf][1], acc[mf][nf], 0, 0, 0);
      }
    cur ^= 1;
  }

  // epilogue: C/D layout col=lane&15, row=4*(lane>>4)+reg (verified m89/m91)
  const int sec = n0 >> 10;   // uniform per block (128 | 1024)
  const float* bb = (mode == 1) ? b0 : (sec == 0) ? b0 : (sec == 1) ? b1 : b2;
  void* outp = (mode == 1) ? o0 : (sec == 0) ? o0 : (sec == 1) ? o1 : o2;
  #pragma unroll
  for (int nf = 0; nf < 4; ++nf) {
    int col = n0 + wn + nf * 16 + c;
    int lc = col & 1023;
    float bvv = bb[lc];
    #pragma unroll
    for (int mf = 0; mf < 4; ++mf) {
      #pragma unroll
      for (int r = 0; r < 4; ++r) {
        int tok = m0 + wm + mf * 16 + 4 * g + r;
        float v = acc[mf][nf][r] + bvv;
        if (mode == 1) {
          ((float*)outp)[(size_t)tok * D_ + col] = v;
        } else {
          if (sec == 0) v *= 0.18033688011112042f;   // (1/8)*log2(e): exp2-domain softmax
          int bi = tok >> 11, si = tok & 2047;
          int h = lc >> 6, hd = lc & 63;
          size_t off = (sec == 2)
            ? ((size_t)(bi * H_ + h) * HD_ + hd) * S_ + si     // V^T
            : ((size_t)(bi * H_ + h) * S_ + si) * HD_ + hd;    // Q / K
          ((ushort*)outp)[off] = f2bf(v);
        }
      }
    }
  }
}

// ---------------- flash attention, swapped-operand (T12 structure) ----------------
// 4 waves x 32 q-rows; KVBLK=64; S^T = mfma(K,Q) so lane owns q-row = lane&31.
// PV as O^T = V^T . P^T : P^T feeds B-operand directly from QK^T output registers.
// Key map per C/D layout (m74/m101): reg r of S^T tile holds key (r&3)+8*(r>>2)+4*hi.
// V A-fragment loads the SAME keys -> k-slot-consistent MFMA. No LDS, no barriers.
__global__ __launch_bounds__(256) void k_attn(const ushort* __restrict__ Q,
                                              const ushort* __restrict__ K,
                                              const ushort* __restrict__ Vt,
                                              ushort* __restrict__ O) {
  const int tid = threadIdx.x;
  const int w = tid >> 6, lane = tid & 63;
  const int ql = lane & 31, hi = lane >> 5;
  // XCD swizzle: wgid%8 = XCD (round-robin); 4 bh per XCD -> K/V sets fit 4MB L2
  const int bid = blockIdx.x;
  const int bh = (bid & 7) * 4 + ((bid >> 3) & 3);
  const int qc = bid >> 5;                  // 0..15
  const int q0 = qc * 128 + w * 32;
  const ushort* Qb = Q + (size_t)bh * S_ * HD_;
  const ushort* Kb = K + (size_t)bh * S_ * HD_;
  const ushort* Vb = Vt + (size_t)bh * HD_ * S_;

  // Q B-fragment (held): contiguous k-map, slot j of MFMA t = dim 16t+8hi+j
  short8 qf[4];
  #pragma unroll
  for (int t = 0; t < 4; ++t)
    qf[t] = *(const short8*)(Qb + (size_t)(q0 + ql) * HD_ + 16 * t + 8 * hi);

  f32x16 oacc[2];
  oacc[0] = 0.f; oacc[1] = 0.f;
  float m = -1e30f, l = 0.f;

  for (int k0 = 0; k0 < S_; k0 += 64) {
    // ---- QK^T: two 32-key S^T tiles ----
    f32x16 st[2];
    #pragma unroll
    for (int n = 0; n < 2; ++n) {
      st[n] = 0.f;
      const ushort* krow = Kb + (size_t)(k0 + 32 * n + ql) * HD_ + 8 * hi;
      #pragma unroll
      for (int t = 0; t < 4; ++t) {
        short8 kf = *(const short8*)(krow + 16 * t);
        st[n] = __builtin_amdgcn_mfma_f32_32x32x16_bf16(kf, qf[t], st[n], 0, 0, 0);
      }
    }
    // ---- online softmax: in-lane over 32 vals + one cross-half exchange ----
    float cmax = st[0][0];
    #pragma unroll
    for (int i = 1; i < 16; ++i) cmax = fmaxf(cmax, st[0][i]);
    #pragma unroll
    for (int i = 0; i < 16; ++i) cmax = fmaxf(cmax, st[1][i]);
    cmax = fmaxf(cmax, __shfl_xor(cmax, 32));
    float mnew = fmaxf(m, cmax);
    float sc = exp2f(m - mnew);
    m = mnew;
    float ps = 0.f;
    #pragma unroll
    for (int n = 0; n < 2; ++n)
      #pragma unroll
      for (int i = 0; i < 16; ++i) {
        float p = exp2f(st[n][i] - mnew);
        st[n][i] = p;
        ps += p;
      }
    ps += __shfl_xor(ps, 32);
    l = l * sc + ps;
    #pragma unroll
    for (int i = 0; i < 16; ++i) { oacc[0][i] *= sc; oacc[1][i] *= sc; }

    // ---- pack P^T to bf16 B-fragments (regs 0..7 -> keys 0..15, 8..15 -> 16..31) ----
    short8 pf[2][2];
    #pragma unroll
    for (int n = 0; n < 2; ++n)
      #pragma unroll
      for (int m2 = 0; m2 < 2; ++m2)
        pf[n][m2] = pk8(st[n][8 * m2 + 0], st[n][8 * m2 + 1], st[n][8 * m2 + 2], st[n][8 * m2 + 3],
                        st[n][8 * m2 + 4], st[n][8 * m2 + 5], st[n][8 * m2 + 6], st[n][8 * m2 + 7]);

    // ---- PV': O^T[d][q] += V^T . P^T ; V A-frag at keys (j&3)+8*(j>>2)+4hi+16m2 ----
    #pragma unroll
    for (int dt = 0; dt < 2; ++dt) {
      const ushort* vrow = Vb + (size_t)(dt * 32 + ql) * S_ + k0 + 4 * hi;
      #pragma unroll
      for (int n = 0; n < 2; ++n)
        #pragma unroll
        for (int m2 = 0; m2 < 2; ++m2) {
          const ushort* vb = vrow + 32 * n + 16 * m2;
          short8 vf = ld2x4(vb, vb + 8);
          oacc[dt] = __builtin_amdgcn_mfma_f32_32x32x16_bf16(vf, pf[n][m2], oacc[dt], 0, 0, 0);
        }
    }
  }

  // ---- epilogue: O[tok][h*64 + d], d = 8*rg + 4hi + i, packed 8B stores ----
  const float invl = 1.f / l;
  const int bi = bh >> 4, h = bh & 15;
  const int tok = bi * S_ + q0 + ql;
  #pragma unroll
  for (int dt = 0; dt < 2; ++dt)
    #pragma unroll
    for (int rg = 0; rg < 4; ++rg) {
      ushort4 u;
      u.x = f2bf(oacc[dt][4 * rg + 0] * invl);
      u.y = f2bf(oacc[dt][4 * rg + 1] * invl);
      u.z = f2bf(oacc[dt][4 * rg + 2] * invl);
      u.w = f2bf(oacc[dt][4 * rg + 3] * invl);
      *(ushort4*)(O + (size_t)tok * D_ + h * 64 + dt * 32 + rg * 8 + 4 * hi) = u;
    }
}

extern "C" void kernel_launch(void* const* d_in, const int* in_sizes, int n_in,
                              void* d_out, int out_size, void* d_ws, size_t ws_size,
                              hipStream_t stream) {
  const float* x  = (const float*)d_in[0];
  const float* Wq = (const float*)d_in[1];
  const float* bq = (const float*)d_in[2];
  const float* Wk = (const float*)d_in[3];
  const float* bk = (const float*)d_in[4];
  const float* Wv = (const float*)d_in[5];
  const float* bv = (const float*)d_in[6];
  const float* Wo = (const float*)d_in[7];
  const float* bo = (const float*)d_in[8];
  char* ws = (char*)d_ws;
  const size_t MB = 1024 * 1024;
  ushort* Xbf = (ushort*)(ws + 0);        // 8 MiB
  ushort* Wt3 = (ushort*)(ws + 8 * MB);   // 6 MiB: [3072][1024] = Wq^T|Wk^T|Wv^T
  ushort* Wto = (ushort*)(ws + 14 * MB);  // 2 MiB
  ushort* Qb  = (ushort*)(ws + 16 * MB);  // 8 MiB each
  ushort* Kb  = (ushort*)(ws + 24 * MB);
  ushort* Vtb = (ushort*)(ws + 32 * MB);
  ushort* Att = (ushort*)(ws + 0);        // reuse Xbf region (dead after QKV GEMM)

  k_cvt_bf16<<<1024, 256, 0, stream>>>(x, Xbf, M_ * D_ / 4);
  k_transpose_w<<<dim3(32, 32, 4), 256, 0, stream>>>(
      Wq, Wk, Wv, Wo, Wt3, Wt3 + 1024 * 1024, Wt3 + 2048 * 1024, Wto);
  k_gemm_bt<<<dim3(24, 32), 256, 0, stream>>>(Xbf, Wt3, bq, bk, bv, Qb, Kb, Vtb, 0);
  k_attn<<<512, 256, 0, stream>>>(Qb, Kb, Vtb, Att);
  k_gemm_bt<<<dim3(8, 32), 256, 0, stream>>>(Att, Wto, bo, bo, bo, d_out, d_out, d_out, 1);
}

// Round 6
// 243.848 us; speedup vs baseline: 1.3954x; 1.3774x over previous
//
#include <hip/hip_runtime.h>
#include <hip/hip_bf16.h>
#include <stdint.h>

#define B_  2
#define S_  2048
#define D_  1024
#define H_  16
#define HD_ 64
#define M_  (B_*S_)   // 4096 tokens

typedef __attribute__((ext_vector_type(8)))  short short8;
typedef __attribute__((ext_vector_type(4)))  float f32x4;
typedef __attribute__((ext_vector_type(16))) float f32x16;

// fp32 -> bf16 round-to-nearest-even
__device__ __forceinline__ unsigned short f2bf(float f) {
  union { float f; unsigned int u; } x; x.f = f;
  unsigned int r = (x.u + 0x7FFFu + ((x.u >> 16) & 1u)) >> 16;
  return (unsigned short)r;
}

// two positive-f32 -> packed bf16 pair (round-half-up) via v_perm byte select
__device__ __forceinline__ unsigned int pack2(float a, float b) {
  union { float f; unsigned int u; } x, y; x.f = a; y.f = b;
  return __builtin_amdgcn_perm(y.u + 0x8000u, x.u + 0x8000u, 0x07060302u);
}

typedef const __attribute__((address_space(1))) unsigned int* gas1_t;
typedef __attribute__((address_space(3))) unsigned int* las3_t;

__device__ __forceinline__ void gload_lds16(const void* g, void* l) {
  __builtin_amdgcn_global_load_lds((gas1_t)g, (las3_t)l, 16, 0, 0);
}

// ---------------- elementwise fp32 -> bf16 ----------------
__global__ void k_cvt_bf16(const float* __restrict__ x, ushort* __restrict__ o, int n4) {
  int i = blockIdx.x * blockDim.x + threadIdx.x;
  int stride = gridDim.x * blockDim.x;
  for (int j = i; j < n4; j += stride) {
    float4 v = ((const float4*)x)[j];
    ushort4 u = make_ushort4(f2bf(v.x), f2bf(v.y), f2bf(v.z), f2bf(v.w));
    ((ushort4*)o)[j] = u;
  }
}

// ---------------- W [k][n] fp32 -> Wt [n][k] bf16 (tiled transpose) ----------------
__global__ void k_transpose_w(const float* __restrict__ w0, const float* __restrict__ w1,
                              const float* __restrict__ w2, const float* __restrict__ w3,
                              ushort* __restrict__ o0, ushort* __restrict__ o1,
                              ushort* __restrict__ o2, ushort* __restrict__ o3) {
  const float* w = (blockIdx.z == 0) ? w0 : (blockIdx.z == 1) ? w1 : (blockIdx.z == 2) ? w2 : w3;
  ushort*      o = (blockIdx.z == 0) ? o0 : (blockIdx.z == 1) ? o1 : (blockIdx.z == 2) ? o2 : o3;
  __shared__ float t[32][33];
  int tx = threadIdx.x & 31, ty = threadIdx.x >> 5;   // 256 threads: 32 x 8
  int kt = blockIdx.y * 32, nt = blockIdx.x * 32;
  #pragma unroll
  for (int i = 0; i < 4; ++i)
    t[ty + 8 * i][tx] = w[(size_t)(kt + ty + 8 * i) * D_ + nt + tx];
  __syncthreads();
  #pragma unroll
  for (int i = 0; i < 4; ++i)
    o[(size_t)(nt + ty + 8 * i) * D_ + kt + tx] = f2bf(t[tx][ty + 8 * i]);
}

// ---------------- bf16 GEMM: out[tok][n] = A[tok][:] . Bt[n][:] + bias ----------------
// mode 0: fused QKV (Bt = [3072][1024]; section by n0>>10: Q scaled, K, V^T)
// mode 1: output projection (fp32 out + bo)
__global__ __launch_bounds__(256) void k_gemm_bt(const ushort* __restrict__ A,
                                                 const ushort* __restrict__ Bt,
                                                 const float* __restrict__ b0,
                                                 const float* __restrict__ b1,
                                                 const float* __restrict__ b2,
                                                 void* __restrict__ o0,
                                                 void* __restrict__ o1,
                                                 void* __restrict__ o2, int mode) {
  __shared__ char smem[2][32768];   // per buffer: A tile 16K | B tile 16K
  const int tid = threadIdx.x;
  const int w = tid >> 6, lane = tid & 63;
  const int g = lane >> 4, c = lane & 15;
  const int m0 = blockIdx.y * 128, n0 = blockIdx.x * 128;
  const int wm = (w >> 1) * 64, wn = (w & 1) * 64;

  f32x4 acc[4][4];
  #pragma unroll
  for (int i = 0; i < 4; ++i)
    #pragma unroll
    for (int j = 0; j < 4; ++j) acc[i][j] = 0.f;

  const char* Abase = (const char*)A + (size_t)m0 * (D_ * 2);
  const char* Bbase = (const char*)Bt + (size_t)n0 * (D_ * 2);

  auto stage = [&](int buf, int kb) {
    char* ls = &smem[buf][0];
    #pragma unroll
    for (int i = 0; i < 4; ++i) {
      int obase = w * 4096 + i * 1024;
      int ot = obase + lane * 16;
      int u = ot ^ (((ot >> 7) & 7) << 4);        // inverse swizzle on SOURCE (rule #21)
      gload_lds16(Abase + (size_t)(u >> 7) * (D_ * 2) + kb * 128 + (u & 127), ls + obase);
    }
    #pragma unroll
    for (int i = 0; i < 4; ++i) {
      int obase = w * 4096 + i * 1024;
      int ot = obase + lane * 16;
      int u = ot ^ (((ot >> 7) & 7) << 4);
      gload_lds16(Bbase + (size_t)(u >> 7) * (D_ * 2) + kb * 128 + (u & 127), ls + 16384 + obase);
    }
  };

  stage(0, 0);
  int cur = 0;
  for (int kb = 0; kb < D_ / 64; ++kb) {
    __syncthreads();
    if (kb < D_ / 64 - 1) stage(cur ^ 1, kb + 1);
    const char* lsA = &smem[cur][0];
    const char* lsB = lsA + 16384;
    short8 a[4][2], b[4][2];
    #pragma unroll
    for (int f = 0; f < 4; ++f) {
      int rowA = wm + f * 16 + c;
      int rowB = wn + f * 16 + c;
      #pragma unroll
      for (int ks = 0; ks < 2; ++ks) {
        int offA = (rowA * 128 + ks * 64 + g * 16) ^ ((rowA & 7) << 4);
        int offB = (rowB * 128 + ks * 64 + g * 16) ^ ((rowB & 7) << 4);
        a[f][ks] = *(const short8*)(lsA + offA);
        b[f][ks] = *(const short8*)(lsB + offB);
      }
    }
    #pragma unroll
    for (int mf = 0; mf < 4; ++mf)
      #pragma unroll
      for (int nf = 0; nf < 4; ++nf) {
        acc[mf][nf] = __builtin_amdgcn_mfma_f32_16x16x32_bf16(a[mf][0], b[nf][0], acc[mf][nf], 0, 0, 0);
        acc[mf][nf] = __builtin_amdgcn_mfma_f32_16x16x32_bf16(a[mf][1], b[nf][1], acc[mf][nf], 0, 0, 0);
      }
    cur ^= 1;
  }

  // epilogue: C/D layout col=lane&15, row=4*(lane>>4)+reg (verified m89/m91)
  const int sec = n0 >> 10;   // uniform per block (128 | 1024)
  const float* bb = (mode == 1) ? b0 : (sec == 0) ? b0 : (sec == 1) ? b1 : b2;
  void* outp = (mode == 1) ? o0 : (sec == 0) ? o0 : (sec == 1) ? o1 : o2;
  #pragma unroll
  for (int nf = 0; nf < 4; ++nf) {
    int col = n0 + wn + nf * 16 + c;
    int lc = col & 1023;
    float bvv = bb[lc];
    #pragma unroll
    for (int mf = 0; mf < 4; ++mf) {
      #pragma unroll
      for (int r = 0; r < 4; ++r) {
        int tok = m0 + wm + mf * 16 + 4 * g + r;
        float v = acc[mf][nf][r] + bvv;
        if (mode == 1) {
          ((float*)outp)[(size_t)tok * D_ + col] = v;
        } else {
          if (sec == 0) v *= 0.18033688011112042f;   // (1/8)*log2(e): exp2-domain softmax
          int bi = tok >> 11, si = tok & 2047;
          int h = lc >> 6, hd = lc & 63;
          size_t off = (sec == 2)
            ? ((size_t)(bi * H_ + h) * HD_ + hd) * S_ + si     // V^T
            : ((size_t)(bi * H_ + h) * S_ + si) * HD_ + hd;    // Q / K
          ((ushort*)outp)[off] = f2bf(v);
        }
      }
    }
  }
}

// ---------------- flash attention v3: LDS-staged K/V (coalesced), swapped-operand ----------------
// 4 waves share (bh, 128-q chunk). Per 64-key tile: K[64][128B] and V^T[64][128B] staged to LDS
// via global_load_lds with both-sides XOR swizzle (rule #21); fragments via ds_read_b128.
// S^T = mfma(K,Q): lane owns q-row = lane&31; reg r of each 32-key tile holds key
// (r&3)+8*(r>>2)+4*hi (m74/m101). P repacked to CONTIGUOUS key order via packed-u32
// shfl_xor(32) exchange, so PV' B-frag slot (hi,j) = key 16*m2+8*hi+j and the matching
// V^T A-frag is one b128 LDS read. Tree reductions for row max/sum.
__global__ __launch_bounds__(256) void k_attn(const ushort* __restrict__ Q,
                                              const ushort* __restrict__ K,
                                              const ushort* __restrict__ Vt,
                                              ushort* __restrict__ O) {
  __shared__ char lds[2][16384];   // per buf: K tile 8KB | V tile 8KB
  const int tid = threadIdx.x;
  const int w = tid >> 6, lane = tid & 63;
  const int ql = lane & 31, hi = lane >> 5;
  // XCD swizzle: wgid%8 = XCD (round-robin); 4 bh per XCD -> K/V sets fit 4MB L2
  const int bid = blockIdx.x;
  const int bh = (bid & 7) * 4 + ((bid >> 3) & 3);
  const int qc = bid >> 5;                  // 0..15
  const int q0 = qc * 128 + w * 32;
  const ushort* Qb = Q + (size_t)bh * S_ * HD_;
  const char* Kb2 = (const char*)(K + (size_t)bh * S_ * HD_);   // row=key, 128B
  const char* Vb2 = (const char*)(Vt + (size_t)bh * HD_ * S_);  // row=d, 4KB

  // Q B-fragment (held): slot (hi,j) of MFMA t = dim 16t+8hi+j (matches K A-frag map)
  short8 qf[4];
  #pragma unroll
  for (int t = 0; t < 4; ++t)
    qf[t] = *(const short8*)(Qb + (size_t)(q0 + ql) * HD_ + 16 * t + 8 * hi);

  auto stageKV = [&](int buf, int k0n) {
    char* ls = &lds[buf][0];
    #pragma unroll
    for (int i = 0; i < 2; ++i) {
      int o = tid * 16 + i * 4096;
      int u = o ^ (((o >> 7) & 7) << 4);          // inverse swizzle on SOURCE
      gload_lds16(Kb2 + (size_t)(k0n + (u >> 7)) * 128 + (u & 127), ls + o);
    }
    #pragma unroll
    for (int i = 0; i < 2; ++i) {
      int o = tid * 16 + i * 4096;
      int u = o ^ (((o >> 7) & 7) << 4);
      gload_lds16(Vb2 + (size_t)(u >> 7) * (S_ * 2) + (size_t)k0n * 2 + (u & 127), ls + 8192 + o);
    }
  };

  f32x16 oacc[2];
  oacc[0] = 0.f; oacc[1] = 0.f;
  float m = -1e30f, l = 0.f;

  stageKV(0, 0);
  int cur = 0;
  for (int k0 = 0; k0 < S_; k0 += 64) {
    __syncthreads();                 // buf[cur] staged (vmcnt drained), prev reads done
    if (k0 + 64 < S_) stageKV(cur ^ 1, k0 + 64);
    const char* lsK = &lds[cur][0];
    const char* lsV = lsK + 8192;

    // ---- QK^T: two 32-key S^T tiles from LDS ----
    f32x16 st[2];
    #pragma unroll
    for (int n = 0; n < 2; ++n) {
      st[n] = 0.f;
      #pragma unroll
      for (int t = 0; t < 4; ++t) {
        int row = 32 * n + ql, col = 32 * t + 16 * hi;
        short8 kf = *(const short8*)(lsK + ((row * 128 + col) ^ ((row & 7) << 4)));
        st[n] = __builtin_amdgcn_mfma_f32_32x32x16_bf16(kf, qf[t], st[n], 0, 0, 0);
      }
    }

    // ---- online softmax: tree max / tree sum + one cross-half exchange ----
    float red[16];
    #pragma unroll
    for (int i = 0; i < 16; ++i) red[i] = fmaxf(st[0][i], st[1][i]);
    #pragma unroll
    for (int s = 8; s >= 1; s >>= 1)
      #pragma unroll
      for (int i = 0; i < s; ++i) red[i] = fmaxf(red[i], red[i + s]);
    float cmax = fmaxf(red[0], __shfl_xor(red[0], 32));
    float mnew = fmaxf(m, cmax);
    float sc = exp2f(m - mnew);
    m = mnew;
    #pragma unroll
    for (int n = 0; n < 2; ++n)
      #pragma unroll
      for (int i = 0; i < 16; ++i) st[n][i] = exp2f(st[n][i] - mnew);
    #pragma unroll
    for (int i = 0; i < 16; ++i) red[i] = st[0][i] + st[1][i];
    #pragma unroll
    for (int s = 8; s >= 1; s >>= 1)
      #pragma unroll
      for (int i = 0; i < s; ++i) red[i] += red[i + s];
    float ps = red[0] + __shfl_xor(red[0], 32);
    l = l * sc + ps;
    #pragma unroll
    for (int i = 0; i < 16; ++i) { oacc[0][i] *= sc; oacc[1][i] *= sc; }

    // ---- pack P to bf16 + redistribute to contiguous key order ----
    // own regs: pk[b] = keys {8b+4hi .. 8b+4hi+3} packed as 2 u32 (b=0..3 per 32-key tile)
    // frag m2 slot (h',j): key 16m2+8h'+j. u32#0,#1 (j=0-3, owner hi=0); u32#2,#3 (j=4-7, owner hi=1).
    short8 pfrag[2][2];
    #pragma unroll
    for (int n = 0; n < 2; ++n) {
      unsigned int pk[4][2];
      #pragma unroll
      for (int b = 0; b < 4; ++b)
        #pragma unroll
        for (int p = 0; p < 2; ++p)
          pk[b][p] = pack2(st[n][4 * b + 2 * p], st[n][4 * b + 2 * p + 1]);
      #pragma unroll
      for (int m2 = 0; m2 < 2; ++m2) {
        union { unsigned int u[4]; short8 v; } fr;
        #pragma unroll
        for (int p = 0; p < 2; ++p) {
          unsigned int xA = (unsigned int)__shfl_xor((int)pk[2 * m2 + 1][p], 32);
          unsigned int xB = (unsigned int)__shfl_xor((int)pk[2 * m2][p], 32);
          fr.u[p]     = hi ? xA : pk[2 * m2][p];       // keys +0..3 (from hi=0 owner)
          fr.u[2 + p] = hi ? pk[2 * m2 + 1][p] : xB;   // keys +4..7 (from hi=1 owner)
        }
        pfrag[n][m2] = fr.v;
      }
    }

    // ---- PV': O^T += V^T . P^T ; A-frag slot (hi,j) = key 64n+32m2... col=64n+32m2+16hi ----
    #pragma unroll
    for (int dt = 0; dt < 2; ++dt)
      #pragma unroll
      for (int n = 0; n < 2; ++n)
        #pragma unroll
        for (int m2 = 0; m2 < 2; ++m2) {
          int row = 32 * dt + ql, col = 64 * n + 32 * m2 + 16 * hi;
          short8 vf = *(const short8*)(lsV + ((row * 128 + col) ^ ((row & 7) << 4)));
          oacc[dt] = __builtin_amdgcn_mfma_f32_32x32x16_bf16(vf, pfrag[n][m2], oacc[dt], 0, 0, 0);
        }
    cur ^= 1;
  }

  // ---- epilogue: O[tok][h*64 + d], d = 8*rg + 4hi + i ----
  const float invl = 1.f / l;
  const int bi = bh >> 4, h = bh & 15;
  const int tok = bi * S_ + q0 + ql;
  #pragma unroll
  for (int dt = 0; dt < 2; ++dt)
    #pragma unroll
    for (int rg = 0; rg < 4; ++rg) {
      ushort4 u;
      u.x = f2bf(oacc[dt][4 * rg + 0] * invl);
      u.y = f2bf(oacc[dt][4 * rg + 1] * invl);
      u.z = f2bf(oacc[dt][4 * rg + 2] * invl);
      u.w = f2bf(oacc[dt][4 * rg + 3] * invl);
      *(ushort4*)(O + (size_t)tok * D_ + h * 64 + dt * 32 + rg * 8 + 4 * hi) = u;
    }
}

extern "C" void kernel_launch(void* const* d_in, const int* in_sizes, int n_in,
                              void* d_out, int out_size, void* d_ws, size_t ws_size,
                              hipStream_t stream) {
  const float* x  = (const float*)d_in[0];
  const float* Wq = (const float*)d_in[1];
  const float* bq = (const float*)d_in[2];
  const float* Wk = (const float*)d_in[3];
  const float* bk = (const float*)d_in[4];
  const float* Wv = (const float*)d_in[5];
  const float* bv = (const float*)d_in[6];
  const float* Wo = (const float*)d_in[7];
  const float* bo = (const float*)d_in[8];
  char* ws = (char*)d_ws;
  const size_t MB = 1024 * 1024;
  ushort* Xbf = (ushort*)(ws + 0);        // 8 MiB
  ushort* Wt3 = (ushort*)(ws + 8 * MB);   // 6 MiB: [3072][1024] = Wq^T|Wk^T|Wv^T
  ushort* Wto = (ushort*)(ws + 14 * MB);  // 2 MiB
  ushort* Qb  = (ushort*)(ws + 16 * MB);  // 8 MiB each
  ushort* Kb  = (ushort*)(ws + 24 * MB);
  ushort* Vtb = (ushort*)(ws + 32 * MB);
  ushort* Att = (ushort*)(ws + 0);        // reuse Xbf region (dead after QKV GEMM)

  k_cvt_bf16<<<1024, 256, 0, stream>>>(x, Xbf, M_ * D_ / 4);
  k_transpose_w<<<dim3(32, 32, 4), 256, 0, stream>>>(
      Wq, Wk, Wv, Wo, Wt3, Wt3 + 1024 * 1024, Wt3 + 2048 * 1024, Wto);
  k_gemm_bt<<<dim3(24, 32), 256, 0, stream>>>(Xbf, Wt3, bq, bk, bv, Qb, Kb, Vtb, 0);
  k_attn<<<512, 256, 0, stream>>>(Qb, Kb, Vtb, Att);
  k_gemm_bt<<<dim3(8, 32), 256, 0, stream>>>(Att, Wto, bo, bo, bo, d_out, d_out, d_out, 1);
}

// Round 7
// 226.283 us; speedup vs baseline: 1.5038x; 1.0776x over previous
//
#include <hip/hip_runtime.h>
#include <hip/hip_bf16.h>
#include <stdint.h>

#define B_  2
#define S_  2048
#define D_  1024
#define H_  16
#define HD_ 64
#define M_  (B_*S_)   // 4096 tokens

typedef __attribute__((ext_vector_type(8)))  short short8;
typedef __attribute__((ext_vector_type(4)))  float f32x4;
typedef __attribute__((ext_vector_type(16))) float f32x16;

// fp32 -> bf16 round-to-nearest-even
__device__ __forceinline__ unsigned short f2bf(float f) {
  union { float f; unsigned int u; } x; x.f = f;
  unsigned int r = (x.u + 0x7FFFu + ((x.u >> 16) & 1u)) >> 16;
  return (unsigned short)r;
}

// two positive-f32 -> packed bf16 pair (round-half-up) via v_perm byte select
__device__ __forceinline__ unsigned int pack2(float a, float b) {
  union { float f; unsigned int u; } x, y; x.f = a; y.f = b;
  return __builtin_amdgcn_perm(y.u + 0x8000u, x.u + 0x8000u, 0x07060302u);
}

typedef const __attribute__((address_space(1))) unsigned int* gas1_t;
typedef __attribute__((address_space(3))) unsigned int* las3_t;

__device__ __forceinline__ void gload_lds16(const void* g, void* l) {
  __builtin_amdgcn_global_load_lds((gas1_t)g, (las3_t)l, 16, 0, 0);
}

// ---------------- elementwise fp32 -> bf16 ----------------
__global__ void k_cvt_bf16(const float* __restrict__ x, ushort* __restrict__ o, int n4) {
  int i = blockIdx.x * blockDim.x + threadIdx.x;
  int stride = gridDim.x * blockDim.x;
  for (int j = i; j < n4; j += stride) {
    float4 v = ((const float4*)x)[j];
    ushort4 u = make_ushort4(f2bf(v.x), f2bf(v.y), f2bf(v.z), f2bf(v.w));
    ((ushort4*)o)[j] = u;
  }
}

// ---------------- W [k][n] fp32 -> Wt [n][k] bf16 (tiled transpose) ----------------
__global__ void k_transpose_w(const float* __restrict__ w0, const float* __restrict__ w1,
                              const float* __restrict__ w2, const float* __restrict__ w3,
                              ushort* __restrict__ o0, ushort* __restrict__ o1,
                              ushort* __restrict__ o2, ushort* __restrict__ o3) {
  const float* w = (blockIdx.z == 0) ? w0 : (blockIdx.z == 1) ? w1 : (blockIdx.z == 2) ? w2 : w3;
  ushort*      o = (blockIdx.z == 0) ? o0 : (blockIdx.z == 1) ? o1 : (blockIdx.z == 2) ? o2 : o3;
  __shared__ float t[32][33];
  int tx = threadIdx.x & 31, ty = threadIdx.x >> 5;   // 256 threads: 32 x 8
  int kt = blockIdx.y * 32, nt = blockIdx.x * 32;
  #pragma unroll
  for (int i = 0; i < 4; ++i)
    t[ty + 8 * i][tx] = w[(size_t)(kt + ty + 8 * i) * D_ + nt + tx];
  __syncthreads();
  #pragma unroll
  for (int i = 0; i < 4; ++i)
    o[(size_t)(nt + ty + 8 * i) * D_ + kt + tx] = f2bf(t[tx][ty + 8 * i]);
}

// ---------------- bf16 GEMM: out[tok][n] = A[tok][:] . Bt[n][:] + bias ----------------
// mode 0: fused QKV (Bt = [3072][1024]; section by n0>>10: Q scaled, K, V^T)
// mode 1: output projection (fp32 out + bo)
__global__ __launch_bounds__(256) void k_gemm_bt(const ushort* __restrict__ A,
                                                 const ushort* __restrict__ Bt,
                                                 const float* __restrict__ b0,
                                                 const float* __restrict__ b1,
                                                 const float* __restrict__ b2,
                                                 void* __restrict__ o0,
                                                 void* __restrict__ o1,
                                                 void* __restrict__ o2, int mode) {
  __shared__ char smem[2][32768];   // per buffer: A tile 16K | B tile 16K
  const int tid = threadIdx.x;
  const int w = tid >> 6, lane = tid & 63;
  const int g = lane >> 4, c = lane & 15;
  const int m0 = blockIdx.y * 128, n0 = blockIdx.x * 128;
  const int wm = (w >> 1) * 64, wn = (w & 1) * 64;

  f32x4 acc[4][4];
  #pragma unroll
  for (int i = 0; i < 4; ++i)
    #pragma unroll
    for (int j = 0; j < 4; ++j) acc[i][j] = 0.f;

  const char* Abase = (const char*)A + (size_t)m0 * (D_ * 2);
  const char* Bbase = (const char*)Bt + (size_t)n0 * (D_ * 2);

  auto stage = [&](int buf, int kb) {
    char* ls = &smem[buf][0];
    #pragma unroll
    for (int i = 0; i < 4; ++i) {
      int obase = w * 4096 + i * 1024;
      int ot = obase + lane * 16;
      int u = ot ^ (((ot >> 7) & 7) << 4);        // inverse swizzle on SOURCE (rule #21)
      gload_lds16(Abase + (size_t)(u >> 7) * (D_ * 2) + kb * 128 + (u & 127), ls + obase);
    }
    #pragma unroll
    for (int i = 0; i < 4; ++i) {
      int obase = w * 4096 + i * 1024;
      int ot = obase + lane * 16;
      int u = ot ^ (((ot >> 7) & 7) << 4);
      gload_lds16(Bbase + (size_t)(u >> 7) * (D_ * 2) + kb * 128 + (u & 127), ls + 16384 + obase);
    }
  };

  stage(0, 0);
  int cur = 0;
  for (int kb = 0; kb < D_ / 64; ++kb) {
    __syncthreads();
    if (kb < D_ / 64 - 1) stage(cur ^ 1, kb + 1);
    const char* lsA = &smem[cur][0];
    const char* lsB = lsA + 16384;
    short8 a[4][2], b[4][2];
    #pragma unroll
    for (int f = 0; f < 4; ++f) {
      int rowA = wm + f * 16 + c;
      int rowB = wn + f * 16 + c;
      #pragma unroll
      for (int ks = 0; ks < 2; ++ks) {
        int offA = (rowA * 128 + ks * 64 + g * 16) ^ ((rowA & 7) << 4);
        int offB = (rowB * 128 + ks * 64 + g * 16) ^ ((rowB & 7) << 4);
        a[f][ks] = *(const short8*)(lsA + offA);
        b[f][ks] = *(const short8*)(lsB + offB);
      }
    }
    #pragma unroll
    for (int mf = 0; mf < 4; ++mf)
      #pragma unroll
      for (int nf = 0; nf < 4; ++nf) {
        acc[mf][nf] = __builtin_amdgcn_mfma_f32_16x16x32_bf16(a[mf][0], b[nf][0], acc[mf][nf], 0, 0, 0);
        acc[mf][nf] = __builtin_amdgcn_mfma_f32_16x16x32_bf16(a[mf][1], b[nf][1], acc[mf][nf], 0, 0, 0);
      }
    cur ^= 1;
  }

  // epilogue: C/D layout col=lane&15, row=4*(lane>>4)+reg (verified m89/m91)
  const int sec = n0 >> 10;   // uniform per block (128 | 1024)
  const float* bb = (mode == 1) ? b0 : (sec == 0) ? b0 : (sec == 1) ? b1 : b2;
  void* outp = (mode == 1) ? o0 : (sec == 0) ? o0 : (sec == 1) ? o1 : o2;
  #pragma unroll
  for (int nf = 0; nf < 4; ++nf) {
    int col = n0 + wn + nf * 16 + c;
    int lc = col & 1023;
    float bvv = bb[lc];
    #pragma unroll
    for (int mf = 0; mf < 4; ++mf) {
      #pragma unroll
      for (int r = 0; r < 4; ++r) {
        int tok = m0 + wm + mf * 16 + 4 * g + r;
        float v = acc[mf][nf][r] + bvv;
        if (mode == 1) {
          ((float*)outp)[(size_t)tok * D_ + col] = v;
        } else {
          if (sec == 0) v *= 0.18033688011112042f;   // (1/8)*log2(e): exp2-domain softmax
          int bi = tok >> 11, si = tok & 2047;
          int h = lc >> 6, hd = lc & 63;
          size_t off = (sec == 2)
            ? ((size_t)(bi * H_ + h) * HD_ + hd) * S_ + si     // V^T
            : ((size_t)(bi * H_ + h) * S_ + si) * HD_ + hd;    // Q / K
          ((ushort*)outp)[off] = f2bf(v);
        }
      }
    }
  }
}

// ---------------- flash attention v4: LDS K/V, owner-order P, defer-max, MFMA row-sum ----------------
// 4 waves share (bh, 128-q chunk); KVBLK=64 double-buffered (32KB LDS).
// S^T = mfma(K,Q): lane owns q-row = lane&31; reg r of each 32-key tile holds key
// (r&3)+8*(r>>2)+4*hi (m74/m101). P stays in OWNER order: pfrag[n][m2] = regs {8m2..8m2+7}
// = B-slot (hi,j) -> key 32n+16m2+8*(j>>2)+4hi+(j&3). V A-frag loads the SAME permuted keys
// as two ds_read_b64 -> zero cross-lane ops for P. Row-sum via ones-MFMA into lacc
// (only lacc[0] rescaled/read). Defer-max (T13, THR=8 in exp2 domain) skips O/l rescale.
__global__ __launch_bounds__(256, 2) void k_attn(const ushort* __restrict__ Q,
                                                 const ushort* __restrict__ K,
                                                 const ushort* __restrict__ Vt,
                                                 ushort* __restrict__ O) {
  __shared__ char lds[2][16384];   // per buf: K tile 8KB | V tile 8KB
  const int tid = threadIdx.x;
  const int w = tid >> 6, lane = tid & 63;
  const int ql = lane & 31, hi = lane >> 5;
  // XCD swizzle: wgid%8 = XCD (round-robin); 4 bh per XCD -> K/V sets fit 4MB L2
  const int bid = blockIdx.x;
  const int bh = (bid & 7) * 4 + ((bid >> 3) & 3);
  const int qc = bid >> 5;                  // 0..15
  const int q0 = qc * 128 + w * 32;
  const ushort* Qb = Q + (size_t)bh * S_ * HD_;
  const char* Kb2 = (const char*)(K + (size_t)bh * S_ * HD_);   // row=key, 128B
  const char* Vb2 = (const char*)(Vt + (size_t)bh * HD_ * S_);  // row=d, 4KB

  // Q B-fragment (held): slot (hi,j) of MFMA t = dim 16t+8hi+j (matches K A-frag map)
  short8 qf[4];
  #pragma unroll
  for (int t = 0; t < 4; ++t)
    qf[t] = *(const short8*)(Qb + (size_t)(q0 + ql) * HD_ + 16 * t + 8 * hi);

  // ones A-fragment for row-sum MFMA (any slot map works: all values 1.0)
  short8 vones;
  #pragma unroll
  for (int i = 0; i < 8; ++i) vones[i] = (short)0x3F80;

  auto stageKV = [&](int buf, int k0n) {
    char* ls = &lds[buf][0];
    #pragma unroll
    for (int i = 0; i < 2; ++i) {
      int o = tid * 16 + i * 4096;
      int u = o ^ (((o >> 7) & 7) << 4);          // inverse swizzle on SOURCE
      gload_lds16(Kb2 + (size_t)(k0n + (u >> 7)) * 128 + (u & 127), ls + o);
    }
    #pragma unroll
    for (int i = 0; i < 2; ++i) {
      int o = tid * 16 + i * 4096;
      int u = o ^ (((o >> 7) & 7) << 4);
      gload_lds16(Vb2 + (size_t)(u >> 7) * (S_ * 2) + (size_t)k0n * 2 + (u & 127), ls + 8192 + o);
    }
  };

  f32x16 oacc[2], lacc;
  oacc[0] = 0.f; oacc[1] = 0.f; lacc = 0.f;
  float m = -1e30f;

  stageKV(0, 0);
  int cur = 0;
  for (int k0 = 0; k0 < S_; k0 += 64) {
    __syncthreads();                 // buf[cur] staged (vmcnt drained), prev reads done
    if (k0 + 64 < S_) stageKV(cur ^ 1, k0 + 64);
    const char* lsK = &lds[cur][0];
    const char* lsV = lsK + 8192;

    // ---- QK^T: two 32-key S^T tiles from LDS ----
    f32x16 st[2];
    #pragma unroll
    for (int n = 0; n < 2; ++n) {
      st[n] = 0.f;
      #pragma unroll
      for (int t = 0; t < 4; ++t) {
        int row = 32 * n + ql, col = 32 * t + 16 * hi;
        short8 kf = *(const short8*)(lsK + ((row * 128 + col) ^ ((row & 7) << 4)));
        st[n] = __builtin_amdgcn_mfma_f32_32x32x16_bf16(kf, qf[t], st[n], 0, 0, 0);
      }
    }

    // ---- chunk max (tree) + cross-half merge ----
    float red[16];
    #pragma unroll
    for (int i = 0; i < 16; ++i) red[i] = fmaxf(st[0][i], st[1][i]);
    #pragma unroll
    for (int s = 8; s >= 1; s >>= 1)
      #pragma unroll
      for (int i = 0; i < s; ++i) red[i] = fmaxf(red[i], red[i + s]);
    float cmax = fmaxf(red[0], __shfl_xor(red[0], 32));

    // ---- defer-max (T13): rescale only when max grew past threshold ----
    if (!__all(cmax - m <= 8.0f)) {
      float mnew = fmaxf(m, cmax);
      float sc = exp2f(m - mnew);
      m = mnew;
      #pragma unroll
      for (int i = 0; i < 16; ++i) { oacc[0][i] *= sc; oacc[1][i] *= sc; }
      lacc[0] *= sc;
    }

    // ---- P = exp2(S - m), pack to bf16 in OWNER order (no cross-lane) ----
    short8 pfrag[2][2];
    #pragma unroll
    for (int n = 0; n < 2; ++n) {
      unsigned int pk[4][2];
      #pragma unroll
      for (int b = 0; b < 4; ++b)
        #pragma unroll
        for (int p = 0; p < 2; ++p)
          pk[b][p] = pack2(exp2f(st[n][4 * b + 2 * p] - m), exp2f(st[n][4 * b + 2 * p + 1] - m));
      #pragma unroll
      for (int m2 = 0; m2 < 2; ++m2) {
        union { unsigned int u[4]; short8 v; } fr;
        fr.u[0] = pk[2 * m2][0];     fr.u[1] = pk[2 * m2][1];
        fr.u[2] = pk[2 * m2 + 1][0]; fr.u[3] = pk[2 * m2 + 1][1];
        pfrag[n][m2] = fr.v;
      }
    }

    // ---- row-sum via ones-MFMA (replaces 31-add tree + shfl); only lacc[0] used ----
    #pragma unroll
    for (int n = 0; n < 2; ++n)
      #pragma unroll
      for (int m2 = 0; m2 < 2; ++m2)
        lacc = __builtin_amdgcn_mfma_f32_32x32x16_bf16(vones, pfrag[n][m2], lacc, 0, 0, 0);

    // ---- PV': O^T += V^T . P^T ; A-frag slot (hi,j) = key 32n+16m2+8*(j>>2)+4hi+(j&3)
    //      = two b64 LDS reads at key-bytes 64n+32m2+8hi and +16 within the 128B row ----
    #pragma unroll
    for (int dt = 0; dt < 2; ++dt) {
      const int rb = (32 * dt + ql) * 128;
      const int sz = (ql & 7) << 4;
      #pragma unroll
      for (int n = 0; n < 2; ++n)
        #pragma unroll
        for (int m2 = 0; m2 < 2; ++m2) {
          const int cb = 64 * n + 32 * m2 + 8 * hi;
          union { struct { unsigned long long a, b; } q; short8 v; } vf;
          vf.q.a = *(const unsigned long long*)(lsV + ((rb + cb) ^ sz));
          vf.q.b = *(const unsigned long long*)(lsV + ((rb + cb + 16) ^ sz));
          oacc[dt] = __builtin_amdgcn_mfma_f32_32x32x16_bf16(vf.v, pfrag[n][m2], oacc[dt], 0, 0, 0);
        }
    }
    cur ^= 1;
  }

  // ---- epilogue: O[tok][h*64 + d], d = 8*rg + 4hi + i ----
  const float invl = 1.f / lacc[0];
  const int bi = bh >> 4, h = bh & 15;
  const int tok = bi * S_ + q0 + ql;
  #pragma unroll
  for (int dt = 0; dt < 2; ++dt)
    #pragma unroll
    for (int rg = 0; rg < 4; ++rg) {
      ushort4 u;
      u.x = f2bf(oacc[dt][4 * rg + 0] * invl);
      u.y = f2bf(oacc[dt][4 * rg + 1] * invl);
      u.z = f2bf(oacc[dt][4 * rg + 2] * invl);
      u.w = f2bf(oacc[dt][4 * rg + 3] * invl);
      *(ushort4*)(O + (size_t)tok * D_ + h * 64 + dt * 32 + rg * 8 + 4 * hi) = u;
    }
}

extern "C" void kernel_launch(void* const* d_in, const int* in_sizes, int n_in,
                              void* d_out, int out_size, void* d_ws, size_t ws_size,
                              hipStream_t stream) {
  const float* x  = (const float*)d_in[0];
  const float* Wq = (const float*)d_in[1];
  const float* bq = (const float*)d_in[2];
  const float* Wk = (const float*)d_in[3];
  const float* bk = (const float*)d_in[4];
  const float* Wv = (const float*)d_in[5];
  const float* bv = (const float*)d_in[6];
  const float* Wo = (const float*)d_in[7];
  const float* bo = (const float*)d_in[8];
  char* ws = (char*)d_ws;
  const size_t MB = 1024 * 1024;
  ushort* Xbf = (ushort*)(ws + 0);        // 8 MiB
  ushort* Wt3 = (ushort*)(ws + 8 * MB);   // 6 MiB: [3072][1024] = Wq^T|Wk^T|Wv^T
  ushort* Wto = (ushort*)(ws + 14 * MB);  // 2 MiB
  ushort* Qb  = (ushort*)(ws + 16 * MB);  // 8 MiB each
  ushort* Kb  = (ushort*)(ws + 24 * MB);
  ushort* Vtb = (ushort*)(ws + 32 * MB);
  ushort* Att = (ushort*)(ws + 0);        // reuse Xbf region (dead after QKV GEMM)

  k_cvt_bf16<<<1024, 256, 0, stream>>>(x, Xbf, M_ * D_ / 4);
  k_transpose_w<<<dim3(32, 32, 4), 256, 0, stream>>>(
      Wq, Wk, Wv, Wo, Wt3, Wt3 + 1024 * 1024, Wt3 + 2048 * 1024, Wto);
  k_gemm_bt<<<dim3(24, 32), 256, 0, stream>>>(Xbf, Wt3, bq, bk, bv, Qb, Kb, Vtb, 0);
  k_attn<<<512, 256, 0, stream>>>(Qb, Kb, Vtb, Att);
  k_gemm_bt<<<dim3(8, 32), 256, 0, stream>>>(Att, Wto, bo, bo, bo, d_out, d_out, d_out, 1);
}